// Round 4
// baseline (52.351 us; speedup 1.0000x reference)
//
#include <hip/hip_runtime.h>

typedef short bf16x8 __attribute__((ext_vector_type(8)));
typedef float f32x4  __attribute__((ext_vector_type(4)));
typedef unsigned short u16;
typedef unsigned int   u32;

#define HH 128
#define WW 128

__device__ __forceinline__ u16 f2bf(float f) {
    union { float f; u32 i; } v; v.f = f;
    u32 x = v.i;
    x += 0x7fffu + ((x >> 16) & 1u);   // round-to-nearest-even
    return (u16)(x >> 16);
}

// Implicit-GEMM conv via 9 shifted 32x32 channel GEMMs on mfma_f32_16x16x32_bf16.
// Block: 512 thr (8 waves), tile = 1 batch x 4 rows x 128 cols x 32 out-ch.
// Wave = (row 0..3, oh 0..1): one output row, 16 of the 32 output channels.
// A-fragments synthesized per-lane in registers (no LDS weight staging).
// Grid: 512 blocks (16 b x 32 row-blocks), XCD-bijective swizzled, 2 blocks/CU.
__global__ __launch_bounds__(512, 4) void geps_mfma_kernel(
    const float* __restrict__ x, const float* __restrict__ codes,
    const float* __restrict__ weight, const float* __restrict__ A,
    const float* __restrict__ Bm, const float* __restrict__ bias,
    const float* __restrict__ bctx, float* __restrict__ out)
{
    // [6 rows][8 slots][4 ig][16 p] x 8ch bf16 = 49152 B (B-frag = 1 linear b128)
    __shared__ bf16x8 lds_x[3072];
    __shared__ float  lds_ctx[576];   // [i][r][kl] = sum_c A[i,c,kl]*codes[c,r]
    __shared__ float  lds_b[32];

    const int tid = threadIdx.x;
    const int l   = tid & 63;
    const int wvid = tid >> 6;         // 0..7
    const int row = wvid >> 1;         // output row within tile
    const int oh  = wvid & 1;          // output-channel half

    // XCD-aware bijective swizzle: 512 blocks = 8 XCDs x 64 contiguous.
    const int orig = blockIdx.x;
    const int vb   = (orig & 7) * 64 + (orig >> 3);
    const int rb   = vb & 31;          // row-block 0..31
    const int b    = vb >> 5;          // batch 0..15
    const int h0   = rb * 4;

    const float c00 = codes[b * 4 + 0];
    const float c01 = codes[b * 4 + 1];
    const float c10 = codes[b * 4 + 2];
    const float c11 = codes[b * 4 + 3];

    // ---- Phase 1: code contraction + per-sample bias ----
    for (int j = tid; j < 576; j += 512) {
        int i = j / 18, rem = j % 18, r = rem / 9, kl = rem % 9;
        float a0 = A[(i * 2 + 0) * 9 + kl];
        float a1 = A[(i * 2 + 1) * 9 + kl];
        lds_ctx[j] = (r == 0) ? (a0 * c00 + a1 * c10) : (a0 * c01 + a1 * c11);
    }
    if (tid < 32) lds_b[tid] = bias[tid] + c00 * bctx[tid] + c11 * bctx[32 + tid];
    __syncthreads();

    // ---- Phase 2a: stage x channel-last bf16 (6 rows, wrap at stage) ----
    // item = (row, ig, col-pair): 8 x float2 global, 2 x b128 LDS write.
    #pragma unroll
    for (int it = 0; it < 3; ++it) {
        int idx = it * 512 + tid;      // < 1536
        int cp  = idx & 63;
        int ig  = (idx >> 6) & 3;
        int rr  = idx >> 8;            // 0..5
        int c0  = cp * 2;
        int grow = (h0 - 1 + rr) & 127;
        const float* src = x + ((size_t)(b * 32 + ig * 8) * HH + grow) * WW + c0;
        bf16x8 v0, v1;
        #pragma unroll
        for (int jj = 0; jj < 8; ++jj) {
            float2 f = *(const float2*)(src + (size_t)jj * HH * WW);
            v0[jj] = (short)f2bf(f.x);
            v1[jj] = (short)f2bf(f.y);
        }
        int didx = rr * 512 + (c0 >> 4) * 64 + ig * 16 + (c0 & 15);
        lds_x[didx]     = v0;
        lds_x[didx + 1] = v1;
    }

    // ---- Phase 2b: synthesize this wave's A-fragments in registers ----
    // A-frag (16x16x32, A = [o x i]): lane l holds o = oh*16+(l&15),
    // i = (l>>4)*8 + jj.  weight/Bm are small & L2-resident.
    const int o_l = oh * 16 + (l & 15);
    const int i0  = (l >> 4) * 8;
    bf16x8 af[9];
    #pragma unroll
    for (int kl = 0; kl < 9; ++kl) {
        float m0 = Bm[(o_l * 2 + 0) * 9 + kl];
        float m1 = Bm[(o_l * 2 + 1) * 9 + kl];
        bf16x8 w8;
        #pragma unroll
        for (int jj = 0; jj < 8; ++jj) {
            int i = i0 + jj;
            float wf = weight[(o_l * 32 + i) * 9 + kl]
                     + lds_ctx[i * 18 + kl] * m0
                     + lds_ctx[i * 18 + 9 + kl] * m1;
            w8[jj] = (short)f2bf(wf);
        }
        af[kl] = w8;
    }
    __syncthreads();

    // ---- B-address bases per tap-column shift dl in {-1,0,1} ----
    const int p = l & 15, igf = l >> 4;
    int bb[3];
    #pragma unroll
    for (int dl = -1; dl <= 1; ++dl) {
        int pq = p + dl;                       // -1..16
        bb[dl + 1] = (pq & 15) + ((pq >> 4) << 6) + igf * 16;  // 16B-elem units
    }

    f32x4 acc[8];
    #pragma unroll
    for (int nt = 0; nt < 8; ++nt) acc[nt] = (f32x4){0.f, 0.f, 0.f, 0.f};

    #pragma unroll
    for (int nt = 0; nt < 8; ++nt) {
        #pragma unroll
        for (int lc = 0; lc < 3; ++lc) {
            int t = (bb[lc] + nt * 64) & 511;  // col wrap within row (512 elems)
            #pragma unroll
            for (int k = 0; k < 3; ++k) {
                bf16x8 bfv = lds_x[(row + k) * 512 + t];
                acc[nt] = __builtin_amdgcn_mfma_f32_16x16x32_bf16(
                    af[k * 3 + lc], bfv, acc[nt], 0, 0, 0);
            }
        }
    }

    // ---- Epilogue: bias + store (D: col=lane&15 -> w, row=(lane>>4)*4+reg -> o) ----
    float blr[4];
    #pragma unroll
    for (int r = 0; r < 4; ++r) blr[r] = lds_b[oh * 16 + (l >> 4) * 4 + r];

    const int h = h0 + row;
    const size_t obase = ((size_t)(b * 32 + oh * 16 + (l >> 4) * 4) * HH + h) * WW + p;
    #pragma unroll
    for (int nt = 0; nt < 8; ++nt)
        #pragma unroll
        for (int r = 0; r < 4; ++r)
            out[obase + (size_t)r * (HH * WW) + nt * 16] = acc[nt][r] + blr[r];
}

extern "C" void kernel_launch(void* const* d_in, const int* in_sizes, int n_in,
                              void* d_out, int out_size, void* d_ws, size_t ws_size,
                              hipStream_t stream) {
    const float* x      = (const float*)d_in[0];
    const float* codes  = (const float*)d_in[1];
    const float* weight = (const float*)d_in[2];
    const float* A      = (const float*)d_in[3];
    const float* Bm     = (const float*)d_in[4];
    const float* bias   = (const float*)d_in[5];
    const float* bctx   = (const float*)d_in[6];
    float* out = (float*)d_out;

    hipLaunchKernelGGL(geps_mfma_kernel, dim3(512), dim3(512), 0, stream,
                       x, codes, weight, A, Bm, bias, bctx, out);
}

// Round 5
// 26.173 us; speedup vs baseline: 2.0002x; 2.0002x over previous
//
#include <hip/hip_runtime.h>

typedef short bf16x8 __attribute__((ext_vector_type(8)));
typedef float f32x4  __attribute__((ext_vector_type(4)));
typedef unsigned short u16;
typedef unsigned int   u32;

#define HH 128
#define WW 128

__device__ __forceinline__ u16 f2bf(float f) {
    union { float f; u32 i; } v; v.f = f;
    u32 x = v.i;
    x += 0x7fffu + ((x >> 16) & 1u);   // round-to-nearest-even
    return (u16)(x >> 16);
}

// Implicit-GEMM conv via 9 shifted 32x32 channel GEMMs on mfma_f32_16x16x32_bf16.
// Block: 512 thr (8 waves), tile = 1 batch x 4 rows x 128 cols x 32 out-ch.
// Wave = (row 0..3, oh 0..1): one output row, 16 of 32 output channels.
// Weights synthesized cooperatively into LDS (coalesced), read as b128 frags.
// Grid: 512 blocks (16 b x 32 row-blocks), XCD-bijective swizzle, 2 blocks/CU.
__global__ __launch_bounds__(512, 2) void geps_mfma_kernel(
    const float* __restrict__ x, const float* __restrict__ codes,
    const float* __restrict__ weight, const float* __restrict__ A,
    const float* __restrict__ Bm, const float* __restrict__ bias,
    const float* __restrict__ bctx, float* __restrict__ out)
{
    // [6 rows][8 slots][4 ig][16 p] x 8ch bf16 = 49152 B (B-frag = 1 linear b128)
    __shared__ bf16x8 lds_x[3072];
    // [9 kl][2 oh][4 kb][16 o] x 8i bf16 = 18432 B (A-frag = 1 linear b128)
    __shared__ bf16x8 lds_w[1152];
    __shared__ float  lds_ctx[576];   // [i][r][kl] = sum_c A[i,c,kl]*codes[c,r]
    __shared__ float  lds_b[32];

    const int tid  = threadIdx.x;
    const int l    = tid & 63;
    const int wvid = tid >> 6;         // 0..7
    const int row  = wvid >> 1;        // output row within tile
    const int oh   = wvid & 1;         // output-channel half

    // XCD-aware bijective swizzle: 512 blocks = 8 XCDs x 64 contiguous.
    const int orig = blockIdx.x;
    const int vb   = (orig & 7) * 64 + (orig >> 3);
    const int rb   = vb & 31;          // row-block 0..31
    const int b    = vb >> 5;          // batch 0..15
    const int h0   = rb * 4;

    const float c00 = codes[b * 4 + 0];
    const float c01 = codes[b * 4 + 1];
    const float c10 = codes[b * 4 + 2];
    const float c11 = codes[b * 4 + 3];

    // ---- Phase 1: code contraction + per-sample bias ----
    for (int j = tid; j < 576; j += 512) {
        int i = j / 18, rem = j % 18, r = rem / 9, kl = rem % 9;
        float a0 = A[(i * 2 + 0) * 9 + kl];
        float a1 = A[(i * 2 + 1) * 9 + kl];
        lds_ctx[j] = (r == 0) ? (a0 * c00 + a1 * c10) : (a0 * c01 + a1 * c11);
    }
    if (tid < 32) lds_b[tid] = bias[tid] + c00 * bctx[tid] + c11 * bctx[32 + tid];
    __syncthreads();

    // ---- Phase 2a: synthesize combined weights -> bf16 LDS (coalesced) ----
    // item = (kl, o, kb); writes 8 contiguous i as one b128.
    for (int j = tid; j < 1152; j += 512) {
        int kl = j >> 7, rem = j & 127, o = rem >> 2, kb = rem & 3;
        float m0 = Bm[(o * 2 + 0) * 9 + kl];
        float m1 = Bm[(o * 2 + 1) * 9 + kl];
        bf16x8 w8;
        #pragma unroll
        for (int jj = 0; jj < 8; ++jj) {
            int i = kb * 8 + jj;
            float wf = weight[(o * 32 + i) * 9 + kl]
                     + lds_ctx[(i * 2 + 0) * 9 + kl] * m0
                     + lds_ctx[(i * 2 + 1) * 9 + kl] * m1;
            w8[jj] = (short)f2bf(wf);
        }
        lds_w[kl * 128 + (o >> 4) * 64 + kb * 16 + (o & 15)] = w8;
    }

    // ---- Phase 2b: stage x channel-last bf16 (6 rows, wrap at stage) ----
    // item = (row, ig, col-pair): 8 x float2 global, 2 x b128 LDS write.
    #pragma unroll
    for (int it = 0; it < 3; ++it) {
        int idx = it * 512 + tid;      // < 1536
        int cp  = idx & 63;
        int ig  = (idx >> 6) & 3;
        int rr  = idx >> 8;            // 0..5
        int c0  = cp * 2;
        int grow = (h0 - 1 + rr) & 127;
        const float* src = x + ((size_t)(b * 32 + ig * 8) * HH + grow) * WW + c0;
        bf16x8 v0, v1;
        #pragma unroll
        for (int jj = 0; jj < 8; ++jj) {
            float2 f = *(const float2*)(src + (size_t)jj * HH * WW);
            v0[jj] = (short)f2bf(f.x);
            v1[jj] = (short)f2bf(f.y);
        }
        int didx = rr * 512 + (c0 >> 4) * 64 + ig * 16 + (c0 & 15);
        lds_x[didx]     = v0;
        lds_x[didx + 1] = v1;
    }
    __syncthreads();

    // ---- A fragments: this wave's 9 taps (36 VGPRs), one b128 each ----
    const int awb = oh * 64 + (l >> 4) * 16 + (l & 15);
    bf16x8 af[9];
    #pragma unroll
    for (int kl = 0; kl < 9; ++kl)
        af[kl] = lds_w[kl * 128 + awb];

    // ---- B-address bases per tap-column shift dl in {-1,0,1} ----
    const int p = l & 15, igf = l >> 4;
    int bb[3];
    #pragma unroll
    for (int dl = -1; dl <= 1; ++dl) {
        int pq = p + dl;                       // -1..16
        bb[dl + 1] = (pq & 15) + ((pq >> 4) << 6) + igf * 16;  // 16B-elem units
    }

    f32x4 acc[8];
    #pragma unroll
    for (int nt = 0; nt < 8; ++nt) acc[nt] = (f32x4){0.f, 0.f, 0.f, 0.f};

    #pragma unroll
    for (int nt = 0; nt < 8; ++nt) {
        #pragma unroll
        for (int lc = 0; lc < 3; ++lc) {
            int t = (bb[lc] + nt * 64) & 511;  // col wrap within row (512 elems)
            #pragma unroll
            for (int k = 0; k < 3; ++k) {
                bf16x8 bfv = lds_x[(row + k) * 512 + t];
                acc[nt] = __builtin_amdgcn_mfma_f32_16x16x32_bf16(
                    af[k * 3 + lc], bfv, acc[nt], 0, 0, 0);
            }
        }
    }

    // ---- Epilogue: bias + store (D: col=lane&15 -> w, row=(lane>>4)*4+reg -> o) ----
    float blr[4];
    #pragma unroll
    for (int r = 0; r < 4; ++r) blr[r] = lds_b[oh * 16 + (l >> 4) * 4 + r];

    const int h = h0 + row;
    const size_t obase = ((size_t)(b * 32 + oh * 16 + (l >> 4) * 4) * HH + h) * WW + p;
    #pragma unroll
    for (int nt = 0; nt < 8; ++nt)
        #pragma unroll
        for (int r = 0; r < 4; ++r)
            out[obase + (size_t)r * (HH * WW) + nt * 16] = acc[nt][r] + blr[r];
}

extern "C" void kernel_launch(void* const* d_in, const int* in_sizes, int n_in,
                              void* d_out, int out_size, void* d_ws, size_t ws_size,
                              hipStream_t stream) {
    const float* x      = (const float*)d_in[0];
    const float* codes  = (const float*)d_in[1];
    const float* weight = (const float*)d_in[2];
    const float* A      = (const float*)d_in[3];
    const float* Bm     = (const float*)d_in[4];
    const float* bias   = (const float*)d_in[5];
    const float* bctx   = (const float*)d_in[6];
    float* out = (float*)d_out;

    hipLaunchKernelGGL(geps_mfma_kernel, dim3(512), dim3(512), 0, stream,
                       x, codes, weight, A, Bm, bias, bctx, out);
}

// Round 6
// 24.491 us; speedup vs baseline: 2.1376x; 1.0687x over previous
//
#include <hip/hip_runtime.h>

typedef short bf16x8 __attribute__((ext_vector_type(8)));
typedef float f32x4  __attribute__((ext_vector_type(4)));
typedef unsigned short u16;
typedef unsigned int   u32;

#define HH 128
#define WW 128

__device__ __forceinline__ u32 cvt_pk_bf16(float lo, float hi) {
    u32 r;
    asm volatile("v_cvt_pk_bf16_f32 %0, %1, %2" : "=v"(r) : "v"(lo), "v"(hi));
    return r;   // low16 = bf16(lo), high16 = bf16(hi)
}

// Implicit-GEMM conv via 9 shifted 32x32 channel GEMMs on mfma_f32_16x16x32_bf16.
// Block: 512 thr (8 waves) owns TWO 4-row tiles (rb, rb+16) of one batch:
//   stage t0 -> compute t0 (with t1 global loads in flight to regs) ->
//   regs->LDS -> compute t1.  Weights/ctx synthesized once, shared by both.
// Wave = (row 0..3, oh 0..1). Grid: 256 blocks (16 b x 16 pairs), 1 block/CU.
__global__ __launch_bounds__(512, 1) void geps_mfma_kernel(
    const float* __restrict__ x, const float* __restrict__ codes,
    const float* __restrict__ weight, const float* __restrict__ A,
    const float* __restrict__ Bm, const float* __restrict__ bias,
    const float* __restrict__ bctx, float* __restrict__ out)
{
    // [6 rows][8 slots][4 ig][16 p] x 8ch bf16 = 49152 B (B-frag = 1 linear b128)
    __shared__ bf16x8 lds_x[3072];
    // [9 kl][2 oh][4 kb][16 o] x 8i bf16 = 18432 B (A-frag = 1 linear b128)
    __shared__ bf16x8 lds_w[1152];
    __shared__ float  lds_ctx[576];   // [i][r][kl] = sum_c A[i,c,kl]*codes[c,r]
    __shared__ float  lds_b[32];

    const int tid  = threadIdx.x;
    const int l    = tid & 63;
    const int wvid = tid >> 6;         // 0..7
    const int row  = wvid >> 1;        // output row within tile
    const int oh   = wvid & 1;         // output-channel half

    // XCD-aware bijective swizzle: 256 blocks = 8 XCDs x 32 contiguous.
    const int orig = blockIdx.x;
    const int vb   = (orig & 7) * 32 + (orig >> 3);
    const int b    = vb >> 4;          // batch 0..15
    const int pair = vb & 15;          // row-tile pair 0..15
    const int h0   = pair * 4;         // tile0 rows h0..h0+3
    const int h1   = h0 + 64;          // tile1 rows

    const float c00 = codes[b * 4 + 0];
    const float c01 = codes[b * 4 + 1];
    const float c10 = codes[b * 4 + 2];
    const float c11 = codes[b * 4 + 3];

    // ---- Phase 1: code contraction + per-sample bias ----
    for (int j = tid; j < 576; j += 512) {
        int i = j / 18, rem = j % 18, r = rem / 9, kl = rem % 9;
        float a0 = A[(i * 2 + 0) * 9 + kl];
        float a1 = A[(i * 2 + 1) * 9 + kl];
        lds_ctx[j] = (r == 0) ? (a0 * c00 + a1 * c10) : (a0 * c01 + a1 * c11);
    }
    if (tid < 32) lds_b[tid] = bias[tid] + c00 * bctx[tid] + c11 * bctx[32 + tid];
    __syncthreads();

    // ---- Phase 2a: synthesize combined weights -> bf16 LDS (coalesced) ----
    for (int j = tid; j < 1152; j += 512) {
        int kl = j >> 7, rem = j & 127, o = rem >> 2, kb = rem & 3;
        float m0 = Bm[(o * 2 + 0) * 9 + kl];
        float m1 = Bm[(o * 2 + 1) * 9 + kl];
        float wf[8];
        #pragma unroll
        for (int jj = 0; jj < 8; ++jj) {
            int i = kb * 8 + jj;
            wf[jj] = weight[(o * 32 + i) * 9 + kl]
                   + lds_ctx[i * 18 + kl] * m0
                   + lds_ctx[i * 18 + 9 + kl] * m1;
        }
        u32 pk[4];
        #pragma unroll
        for (int q = 0; q < 4; ++q) pk[q] = cvt_pk_bf16(wf[2 * q], wf[2 * q + 1]);
        *(uint4*)&lds_w[kl * 128 + (o >> 4) * 64 + kb * 16 + (o & 15)] =
            make_uint4(pk[0], pk[1], pk[2], pk[3]);
    }

    // ---- Phase 2b: stage tile0 x channel-last bf16 (6 rows, wrap at stage) ----
    #pragma unroll
    for (int it = 0; it < 3; ++it) {
        int idx = it * 512 + tid;      // < 1536
        int cp  = idx & 63;
        int ig  = (idx >> 6) & 3;
        int rr  = idx >> 8;            // 0..5
        int c0  = cp * 2;
        int grow = (h0 - 1 + rr) & 127;
        const float* src = x + ((size_t)(b * 32 + ig * 8) * HH + grow) * WW + c0;
        float2 f[8];
        #pragma unroll
        for (int jj = 0; jj < 8; ++jj)
            f[jj] = *(const float2*)(src + (size_t)jj * HH * WW);
        u32 p0[4], p1[4];
        #pragma unroll
        for (int q = 0; q < 4; ++q) {
            p0[q] = cvt_pk_bf16(f[2 * q].x, f[2 * q + 1].x);
            p1[q] = cvt_pk_bf16(f[2 * q].y, f[2 * q + 1].y);
        }
        int didx = rr * 512 + (c0 >> 4) * 64 + ig * 16 + (c0 & 15);
        *(uint4*)&lds_x[didx]     = make_uint4(p0[0], p0[1], p0[2], p0[3]);
        *(uint4*)&lds_x[didx + 1] = make_uint4(p1[0], p1[1], p1[2], p1[3]);
    }
    __syncthreads();

    // ---- A fragments: this wave's 9 taps (36 VGPRs), shared by both tiles ----
    const int awb = oh * 64 + (l >> 4) * 16 + (l & 15);
    bf16x8 af[9];
    #pragma unroll
    for (int kl = 0; kl < 9; ++kl)
        af[kl] = lds_w[kl * 128 + awb];

    // ---- B-address bases per tap-column shift dl in {-1,0,1} ----
    const int p = l & 15, igf = l >> 4;
    int bb[3];
    #pragma unroll
    for (int dl = -1; dl <= 1; ++dl) {
        int pq = p + dl;                       // -1..16
        bb[dl + 1] = (pq & 15) + ((pq >> 4) << 6) + igf * 16;  // 16B-elem units
    }

    float blr[4];
    #pragma unroll
    for (int r = 0; r < 4; ++r) blr[r] = lds_b[oh * 16 + (l >> 4) * 4 + r];

    auto compute_store = [&](int hbase) {
        f32x4 acc[8];
        #pragma unroll
        for (int nt = 0; nt < 8; ++nt) acc[nt] = (f32x4){0.f, 0.f, 0.f, 0.f};
        #pragma unroll
        for (int nt = 0; nt < 8; ++nt) {
            #pragma unroll
            for (int lc = 0; lc < 3; ++lc) {
                int t = (bb[lc] + nt * 64) & 511;  // col wrap (512 elems/row)
                #pragma unroll
                for (int k = 0; k < 3; ++k) {
                    bf16x8 bfv = lds_x[(row + k) * 512 + t];
                    acc[nt] = __builtin_amdgcn_mfma_f32_16x16x32_bf16(
                        af[k * 3 + lc], bfv, acc[nt], 0, 0, 0);
                }
            }
        }
        // D: col=lane&15 -> w, row=(lane>>4)*4+reg -> o
        const int h = hbase + row;
        const size_t obase =
            ((size_t)(b * 32 + oh * 16 + (l >> 4) * 4) * HH + h) * WW + p;
        #pragma unroll
        for (int nt = 0; nt < 8; ++nt)
            #pragma unroll
            for (int r = 0; r < 4; ++r)
                out[obase + (size_t)r * (HH * WW) + nt * 16] = acc[nt][r] + blr[r];
    };

    // ---- Prefetch tile1 into registers (loads in flight during compute0) ----
    float2 pf[24];
    #pragma unroll
    for (int it = 0; it < 3; ++it) {
        int idx = it * 512 + tid;
        int cp  = idx & 63;
        int ig  = (idx >> 6) & 3;
        int rr  = idx >> 8;
        int grow = (h1 - 1 + rr) & 127;
        const float* src = x + ((size_t)(b * 32 + ig * 8) * HH + grow) * WW + cp * 2;
        #pragma unroll
        for (int jj = 0; jj < 8; ++jj)
            pf[it * 8 + jj] = *(const float2*)(src + (size_t)jj * HH * WW);
    }

    compute_store(h0);

    __syncthreads();   // everyone done reading lds_x (tile0)

    // ---- Write prefetched tile1 to LDS ----
    #pragma unroll
    for (int it = 0; it < 3; ++it) {
        int idx = it * 512 + tid;
        int cp  = idx & 63;
        int ig  = (idx >> 6) & 3;
        int rr  = idx >> 8;
        int c0  = cp * 2;
        u32 p0[4], p1[4];
        #pragma unroll
        for (int q = 0; q < 4; ++q) {
            p0[q] = cvt_pk_bf16(pf[it * 8 + 2 * q].x, pf[it * 8 + 2 * q + 1].x);
            p1[q] = cvt_pk_bf16(pf[it * 8 + 2 * q].y, pf[it * 8 + 2 * q + 1].y);
        }
        int didx = rr * 512 + (c0 >> 4) * 64 + ig * 16 + (c0 & 15);
        *(uint4*)&lds_x[didx]     = make_uint4(p0[0], p0[1], p0[2], p0[3]);
        *(uint4*)&lds_x[didx + 1] = make_uint4(p1[0], p1[1], p1[2], p1[3]);
    }
    __syncthreads();

    compute_store(h1);
}

extern "C" void kernel_launch(void* const* d_in, const int* in_sizes, int n_in,
                              void* d_out, int out_size, void* d_ws, size_t ws_size,
                              hipStream_t stream) {
    const float* x      = (const float*)d_in[0];
    const float* codes  = (const float*)d_in[1];
    const float* weight = (const float*)d_in[2];
    const float* A      = (const float*)d_in[3];
    const float* Bm     = (const float*)d_in[4];
    const float* bias   = (const float*)d_in[5];
    const float* bctx   = (const float*)d_in[6];
    float* out = (float*)d_out;

    hipLaunchKernelGGL(geps_mfma_kernel, dim3(256), dim3(512), 0, stream,
                       x, codes, weight, A, Bm, bias, bctx, out);
}

// Round 7
// 23.535 us; speedup vs baseline: 2.2243x; 1.0406x over previous
//
#include <hip/hip_runtime.h>

typedef short bf16x8 __attribute__((ext_vector_type(8)));
typedef float f32x4  __attribute__((ext_vector_type(4)));
typedef unsigned short u16;
typedef unsigned int   u32;

#define HH 128
#define WW 128

__device__ __forceinline__ u32 cvt_pk_bf16(float lo, float hi) {
    u32 r;
    asm volatile("v_cvt_pk_bf16_f32 %0, %1, %2" : "=v"(r) : "v"(lo), "v"(hi));
    return r;   // low16 = bf16(lo), high16 = bf16(hi)
}

// Implicit-GEMM conv via 9 shifted 32x32 channel GEMMs on mfma_f32_16x16x32_bf16.
// Block: 512 thr (8 waves) owns 8 CONTIGUOUS output rows (two 4-row chunks).
// Wave = (row 0..3, nh 0..1): one output row, ALL 32 out-ch, 4 of 8 col-tiles
//   -> each B-frag ds_read_b128 feeds 2 MFMAs (halves LDS read traffic).
// x staged in a rolling 6-row-slot LDS buffer (slot = staged-row mod 6);
// chunk1's 4 new rows are prefetched to regs during chunk0 compute (T14).
// Grid: 256 blocks (16 b x 16 groups), XCD-bijective swizzle, 1 block/CU.
__global__ __launch_bounds__(512, 1) void geps_mfma_kernel(
    const float* __restrict__ x, const float* __restrict__ codes,
    const float* __restrict__ weight, const float* __restrict__ A,
    const float* __restrict__ Bm, const float* __restrict__ bias,
    const float* __restrict__ bctx, float* __restrict__ out)
{
    // [6 slots][8 col-slots][4 ig][16 p] x 8ch bf16 = 49152 B
    __shared__ bf16x8 lds_x[3072];
    // [9 kl][2 oh][4 kb][16 o] x 8i bf16 = 18432 B (A-frag = 1 linear b128)
    __shared__ bf16x8 lds_w[1152];
    __shared__ float  lds_ctx[576];   // [i][r][kl] = sum_c A[i,c,kl]*codes[c,r]
    __shared__ float  lds_b[32];

    const int tid  = threadIdx.x;
    const int l    = tid & 63;
    const int wvid = tid >> 6;         // 0..7
    const int row  = wvid >> 1;        // output row within chunk
    const int nh   = wvid & 1;         // column-tile half: nt = nh*4 + 0..3

    // XCD-aware bijective swizzle: 256 blocks = 8 XCDs x 32 contiguous.
    const int orig = blockIdx.x;
    const int vb   = (orig & 7) * 32 + (orig >> 3);
    const int b    = vb >> 4;          // batch 0..15
    const int grp  = vb & 15;          // 8-row group 0..15
    const int h0   = grp * 8;          // rows h0..h0+7

    const float c00 = codes[b * 4 + 0];
    const float c01 = codes[b * 4 + 1];
    const float c10 = codes[b * 4 + 2];
    const float c11 = codes[b * 4 + 3];

    // ---- Phase 1: code contraction + per-sample bias ----
    for (int j = tid; j < 576; j += 512) {
        int i = j / 18, rem = j % 18, r = rem / 9, kl = rem % 9;
        float a0 = A[(i * 2 + 0) * 9 + kl];
        float a1 = A[(i * 2 + 1) * 9 + kl];
        lds_ctx[j] = (r == 0) ? (a0 * c00 + a1 * c10) : (a0 * c01 + a1 * c11);
    }
    if (tid < 32) lds_b[tid] = bias[tid] + c00 * bctx[tid] + c11 * bctx[32 + tid];
    __syncthreads();

    // ---- Phase 2a: synthesize combined weights -> bf16 LDS (coalesced) ----
    for (int j = tid; j < 1152; j += 512) {
        int kl = j >> 7, rem = j & 127, o = rem >> 2, kb = rem & 3;
        float m0 = Bm[(o * 2 + 0) * 9 + kl];
        float m1 = Bm[(o * 2 + 1) * 9 + kl];
        float wf[8];
        #pragma unroll
        for (int jj = 0; jj < 8; ++jj) {
            int i = kb * 8 + jj;
            wf[jj] = weight[(o * 32 + i) * 9 + kl]
                   + lds_ctx[i * 18 + kl] * m0
                   + lds_ctx[i * 18 + 9 + kl] * m1;
        }
        u32 pk[4];
        #pragma unroll
        for (int q = 0; q < 4; ++q) pk[q] = cvt_pk_bf16(wf[2 * q], wf[2 * q + 1]);
        *(uint4*)&lds_w[kl * 128 + (o >> 4) * 64 + kb * 16 + (o & 15)] =
            make_uint4(pk[0], pk[1], pk[2], pk[3]);
    }

    // ---- Phase 2b: stage rows r=0..5 (global h0-1..h0+4) into slots 0..5 ----
    #pragma unroll
    for (int it = 0; it < 3; ++it) {
        int idx = it * 512 + tid;      // < 1536
        int cp  = idx & 63;
        int ig  = (idx >> 6) & 3;
        int rr  = idx >> 8;            // 0..5
        int c0  = cp * 2;
        int grow = (h0 - 1 + rr) & 127;
        const float* src = x + ((size_t)(b * 32 + ig * 8) * HH + grow) * WW + c0;
        float2 f[8];
        #pragma unroll
        for (int jj = 0; jj < 8; ++jj)
            f[jj] = *(const float2*)(src + (size_t)jj * HH * WW);
        u32 p0[4], p1[4];
        #pragma unroll
        for (int q = 0; q < 4; ++q) {
            p0[q] = cvt_pk_bf16(f[2 * q].x, f[2 * q + 1].x);
            p1[q] = cvt_pk_bf16(f[2 * q].y, f[2 * q + 1].y);
        }
        int didx = rr * 512 + (c0 >> 4) * 64 + ig * 16 + (c0 & 15);
        *(uint4*)&lds_x[didx]     = make_uint4(p0[0], p0[1], p0[2], p0[3]);
        *(uint4*)&lds_x[didx + 1] = make_uint4(p1[0], p1[1], p1[2], p1[3]);
    }
    __syncthreads();

    // ---- A fragments: all 9 taps x both oh halves (72 VGPRs) ----
    const int awb = (l >> 4) * 16 + (l & 15);
    bf16x8 af[9][2];
    #pragma unroll
    for (int kl = 0; kl < 9; ++kl)
        #pragma unroll
        for (int oh = 0; oh < 2; ++oh)
            af[kl][oh] = lds_w[kl * 128 + oh * 64 + awb];

    // ---- B-address bases per tap-column shift dl in {-1,0,1} ----
    const int p = l & 15, igf = l >> 4;
    int bb[3];
    #pragma unroll
    for (int dl = -1; dl <= 1; ++dl) {
        int pq = p + dl;                       // -1..16
        bb[dl + 1] = (pq & 15) + ((pq >> 4) << 6) + igf * 16;  // 16B-elem units
    }

    float blr[2][4];
    #pragma unroll
    for (int oh = 0; oh < 2; ++oh)
        #pragma unroll
        for (int r = 0; r < 4; ++r)
            blr[oh][r] = lds_b[oh * 16 + (l >> 4) * 4 + r];

    // s0..s2: LDS slot for tap k=0..2; h = output row.
    auto compute_store = [&](int s0, int s1, int s2, int h) {
        f32x4 acc[2][4];
        #pragma unroll
        for (int oh = 0; oh < 2; ++oh)
            #pragma unroll
            for (int q = 0; q < 4; ++q) acc[oh][q] = (f32x4){0.f, 0.f, 0.f, 0.f};
        const int sl[3] = {s0, s1, s2};
        #pragma unroll
        for (int q = 0; q < 4; ++q) {
            const int nt = nh * 4 + q;
            #pragma unroll
            for (int lc = 0; lc < 3; ++lc) {
                int t = (bb[lc] + nt * 64) & 511;  // col wrap (512 elems/row)
                #pragma unroll
                for (int k = 0; k < 3; ++k) {
                    bf16x8 bfv = lds_x[sl[k] * 512 + t];
                    acc[0][q] = __builtin_amdgcn_mfma_f32_16x16x32_bf16(
                        af[k * 3 + lc][0], bfv, acc[0][q], 0, 0, 0);
                    acc[1][q] = __builtin_amdgcn_mfma_f32_16x16x32_bf16(
                        af[k * 3 + lc][1], bfv, acc[1][q], 0, 0, 0);
                }
            }
        }
        // D: col=lane&15 -> w, row=(lane>>4)*4+reg -> o
        const size_t obase =
            ((size_t)(b * 32 + (l >> 4) * 4) * HH + h) * WW + p;
        #pragma unroll
        for (int oh = 0; oh < 2; ++oh)
            #pragma unroll
            for (int q = 0; q < 4; ++q)
                #pragma unroll
                for (int r = 0; r < 4; ++r)
                    out[obase + (size_t)(oh * 16 + r) * (HH * WW) + (nh * 4 + q) * 16] =
                        acc[oh][q][r] + blr[oh][r];
    };

    // ---- Prefetch chunk1's 4 new rows (r=6..9 -> slots 0..3) into regs ----
    float2 pf[16];
    #pragma unroll
    for (int it = 0; it < 2; ++it) {
        int idx = it * 512 + tid;      // < 1024
        int cp  = idx & 63;
        int ig  = (idx >> 6) & 3;
        int rr  = idx >> 8;            // 0..3
        int grow = (h0 + 5 + rr) & 127;
        const float* src = x + ((size_t)(b * 32 + ig * 8) * HH + grow) * WW + cp * 2;
        #pragma unroll
        for (int jj = 0; jj < 8; ++jj)
            pf[it * 8 + jj] = *(const float2*)(src + (size_t)jj * HH * WW);
    }

    // ---- Chunk0: out rows h0+row, taps at slots row..row+2 ----
    compute_store(row, row + 1, row + 2, h0 + row);

    __syncthreads();   // all chunk0 LDS reads done

    // ---- Write prefetched rows to slots 0..3 ----
    #pragma unroll
    for (int it = 0; it < 2; ++it) {
        int idx = it * 512 + tid;
        int cp  = idx & 63;
        int ig  = (idx >> 6) & 3;
        int rr  = idx >> 8;
        int c0  = cp * 2;
        u32 p0[4], p1[4];
        #pragma unroll
        for (int q = 0; q < 4; ++q) {
            p0[q] = cvt_pk_bf16(pf[it * 8 + 2 * q].x, pf[it * 8 + 2 * q + 1].x);
            p1[q] = cvt_pk_bf16(pf[it * 8 + 2 * q].y, pf[it * 8 + 2 * q + 1].y);
        }
        int didx = rr * 512 + (c0 >> 4) * 64 + ig * 16 + (c0 & 15);
        *(uint4*)&lds_x[didx]     = make_uint4(p0[0], p0[1], p0[2], p0[3]);
        *(uint4*)&lds_x[didx + 1] = make_uint4(p1[0], p1[1], p1[2], p1[3]);
    }
    __syncthreads();

    // ---- Chunk1: out row h0+4+row needs staged rows r=4+row..6+row (mod 6) ----
    {
        int r0 = 4 + row, r1 = 5 + row, r2 = 6 + row;
        compute_store(r0 >= 6 ? r0 - 6 : r0,
                      r1 >= 6 ? r1 - 6 : r1,
                      r2 >= 6 ? r2 - 6 : r2,
                      h0 + 4 + row);
    }
}

extern "C" void kernel_launch(void* const* d_in, const int* in_sizes, int n_in,
                              void* d_out, int out_size, void* d_ws, size_t ws_size,
                              hipStream_t stream) {
    const float* x      = (const float*)d_in[0];
    const float* codes  = (const float*)d_in[1];
    const float* weight = (const float*)d_in[2];
    const float* A      = (const float*)d_in[3];
    const float* Bm     = (const float*)d_in[4];
    const float* bias   = (const float*)d_in[5];
    const float* bctx   = (const float*)d_in[6];
    float* out = (float*)d_out;

    hipLaunchKernelGGL(geps_mfma_kernel, dim3(256), dim3(512), 0, stream,
                       x, codes, weight, A, Bm, bias, bctx, out);
}